// Round 8
// baseline (835.763 us; speedup 1.0000x reference)
//
#include <hip/hip_runtime.h>
#include <hip/hip_bf16.h>

// GINE backbone, 3 layers. N=50000, E=500000, IN=27, ED=12, H=128.
// Round 6 -> 7 (resubmit; r7 GPU timeout): (1) GEMM A-tile LDS rows padded
// 64B->80B to kill 8-way ds_read_b128 bank conflicts; (2) finalize_bn folded
// into consumers, 6 repacks fused into one upfront launch, one upfront stats
// memset (32 -> 21 dispatches); (3) gather128 tail predicated.

typedef __attribute__((ext_vector_type(8))) short bf16x8;
typedef __attribute__((ext_vector_type(4))) float f32x4;

static inline int cdiv(int a, int b) { return (a + b - 1) / b; }

__device__ inline ushort f2bf(float f) {
    uint32_t u = __float_as_uint(f);
    return (ushort)((u + 0x7FFFu + ((u >> 16) & 1u)) >> 16);
}
__device__ inline float bf2f(ushort h) { return __uint_as_float(((uint32_t)h) << 16); }

// ---------------------------------------------------------------- CSR build
__global__ __launch_bounds__(256) void histogram_dst(const int* __restrict__ dst,
                                                     int* __restrict__ deg, int E) {
    int i = blockIdx.x * blockDim.x + threadIdx.x;
    int stride = gridDim.x * blockDim.x;
    for (; i < E; i += stride) atomicAdd(&deg[dst[i]], 1);
}

__global__ __launch_bounds__(1024) void scan_deg(const int* __restrict__ deg,
                                                 int* __restrict__ rowptr, int N) {
    __shared__ int part[1024];
    int t = threadIdx.x;
    int chunk = (N + 1023) / 1024;
    int b = t * chunk;
    int e = b + chunk;
    if (b > N) b = N;
    if (e > N) e = N;
    int s = 0;
    for (int i = b; i < e; ++i) s += deg[i];
    part[t] = s;
    __syncthreads();
    for (int off = 1; off < 1024; off <<= 1) {
        int v = (t >= off) ? part[t - off] : 0;
        __syncthreads();
        part[t] += v;
        __syncthreads();
    }
    int base = (t == 0) ? 0 : part[t - 1];
    for (int i = b; i < e; ++i) {
        rowptr[i] = base;
        base += deg[i];
    }
    if (t == 1023) rowptr[N] = base;
}

__global__ __launch_bounds__(256) void scatter_edges(const int* __restrict__ dst,
                                                     int* __restrict__ cursor,
                                                     int* __restrict__ eid, int E) {
    int i = blockIdx.x * blockDim.x + threadIdx.x;
    int stride = gridDim.x * blockDim.x;
    for (; i < E; i += stride) {
        int pos = atomicAdd(&cursor[dst[i]], 1);
        eid[pos] = i;
    }
}

// ---------------------------------------------------------------- gather IND=128
// 32 lanes per node, 4 dims/lane (float4), 4 edges in flight, predicated tail.
__global__ __launch_bounds__(256) void gather128(
    const int* __restrict__ rowptr, const int* __restrict__ eid, const int* __restrict__ src,
    const float* __restrict__ ea, const float* __restrict__ eW, const float* __restrict__ eb,
    const float* __restrict__ x, const float* __restrict__ epsp, float* __restrict__ agg, int N) {
    __shared__ __align__(16) float sW[12 * 128];
    __shared__ __align__(16) float sb[128];
    int tid = threadIdx.x;
    for (int i = tid; i < 12 * 128; i += 256) sW[i] = eW[i];
    if (tid < 128) sb[tid] = eb[tid];
    __syncthreads();

    float onePlusEps = 1.0f + *epsp;
    int lane = tid & 31;
    int n = blockIdx.x * 8 + (tid >> 5);
    if (n >= N) return;
    int beg = rowptr[n], end = rowptr[n + 1];
    int d0 = lane << 2;
    float4 bb = *(const float4*)&sb[d0];
    float4 acc = make_float4(0.f, 0.f, 0.f, 0.f);

    int iters = (end - beg + 3) >> 2;
    for (int it = 0; it < iters; ++it) {
        int i = beg + it * 4;
        int e[4], s[4];
        float av[4];
        float4 xv[4], p[4];
#pragma unroll
        for (int j = 0; j < 4; ++j) {
            int idx = i + j;
            e[j] = eid[(idx < end) ? idx : i];  // safe dup; masked below
        }
#pragma unroll
        for (int j = 0; j < 4; ++j) {
            s[j] = src[e[j]];
            av[j] = (lane < 12) ? ea[(size_t)e[j] * 12 + lane] : 0.0f;
        }
#pragma unroll
        for (int j = 0; j < 4; ++j) {
            xv[j] = *(const float4*)&x[(size_t)s[j] * 128 + d0];
            p[j] = bb;
        }
#pragma unroll
        for (int k = 0; k < 12; ++k) {
            float4 w = *(const float4*)&sW[k * 128 + d0];
#pragma unroll
            for (int j = 0; j < 4; ++j) {
                float a = __shfl(av[j], k, 32);
                p[j].x = fmaf(a, w.x, p[j].x);
                p[j].y = fmaf(a, w.y, p[j].y);
                p[j].z = fmaf(a, w.z, p[j].z);
                p[j].w = fmaf(a, w.w, p[j].w);
            }
        }
#pragma unroll
        for (int j = 0; j < 4; ++j) {
            bool v = (i + j) < end;
            acc.x += v ? fmaxf(xv[j].x + p[j].x, 0.f) : 0.f;
            acc.y += v ? fmaxf(xv[j].y + p[j].y, 0.f) : 0.f;
            acc.z += v ? fmaxf(xv[j].z + p[j].z, 0.f) : 0.f;
            acc.w += v ? fmaxf(xv[j].w + p[j].w, 0.f) : 0.f;
        }
    }
    float4 xn = *(const float4*)&x[(size_t)n * 128 + d0];
    float4 o;
    o.x = fmaf(onePlusEps, xn.x, acc.x);
    o.y = fmaf(onePlusEps, xn.y, acc.y);
    o.z = fmaf(onePlusEps, xn.z, acc.z);
    o.w = fmaf(onePlusEps, xn.w, acc.w);
    *(float4*)&agg[(size_t)n * 128 + d0] = o;
}

// ---------------------------------------------------------------- gather IND=27
// 32 lanes per node = 4 sub-groups of 8 lanes; each sub owns one edge.
__global__ __launch_bounds__(256) void gather27(
    const int* __restrict__ rowptr, const int* __restrict__ eid, const int* __restrict__ src,
    const float* __restrict__ ea, const float* __restrict__ eW, const float* __restrict__ eb,
    const float* __restrict__ x, const float* __restrict__ epsp, float* __restrict__ agg, int N) {
    __shared__ __align__(16) float sW[12 * 28 + 4];
    __shared__ __align__(16) float sb[32];
    int tid = threadIdx.x;
    for (int i = tid; i < 12 * 28 + 4; i += 256) sW[i] = 0.0f;
    if (tid < 32) sb[tid] = 0.0f;
    __syncthreads();
    for (int i = tid; i < 12 * 27; i += 256) {
        int k = i / 27, d = i - k * 27;
        sW[k * 28 + d] = eW[i];
    }
    if (tid < 27) sb[tid] = eb[tid];
    __syncthreads();

    float onePlusEps = 1.0f + *epsp;
    int lane = tid & 31;
    int n = blockIdx.x * 8 + (tid >> 5);
    if (n >= N) return;
    int beg = rowptr[n], end = rowptr[n + 1];
    int sub = lane >> 3, sl = lane & 7;
    int d0 = sl << 2;
    int d0c = (sl < 7) ? d0 : 24;
    float4 bb = *(const float4*)&sb[d0c];
    float4 acc = make_float4(0.f, 0.f, 0.f, 0.f);

    int iters = (end - beg + 3) >> 2;
    for (int it = 0; it < iters; ++it) {
        int i = beg + it * 4 + sub;
        bool v = i < end;
        int e = v ? eid[i] : 0;
        int s = v ? src[e] : 0;
        float avA = v ? ea[(size_t)e * 12 + sl] : 0.0f;
        float avB = (v && sl < 4) ? ea[(size_t)e * 12 + 8 + sl] : 0.0f;
        float4 xv = make_float4(0.f, 0.f, 0.f, 0.f);
        if (v) {
            if (sl < 6) {
                xv = *(const float4*)&x[(size_t)s * 27 + d0];
            } else if (sl == 6) {
                xv.x = x[(size_t)s * 27 + 24];
                xv.y = x[(size_t)s * 27 + 25];
                xv.z = x[(size_t)s * 27 + 26];
            }
        }
        float4 p = bb;
#pragma unroll
        for (int k = 0; k < 8; ++k) {
            float ak = __shfl(avA, k, 8);
            float4 w = *(const float4*)&sW[k * 28 + d0c];
            p.x = fmaf(ak, w.x, p.x);
            p.y = fmaf(ak, w.y, p.y);
            p.z = fmaf(ak, w.z, p.z);
            p.w = fmaf(ak, w.w, p.w);
        }
#pragma unroll
        for (int k = 8; k < 12; ++k) {
            float ak = __shfl(avB, k - 8, 8);
            float4 w = *(const float4*)&sW[k * 28 + d0c];
            p.x = fmaf(ak, w.x, p.x);
            p.y = fmaf(ak, w.y, p.y);
            p.z = fmaf(ak, w.z, p.z);
            p.w = fmaf(ak, w.w, p.w);
        }
        if (v) {
            acc.x += fmaxf(xv.x + p.x, 0.f);
            acc.y += fmaxf(xv.y + p.y, 0.f);
            acc.z += fmaxf(xv.z + p.z, 0.f);
            acc.w += fmaxf(xv.w + p.w, 0.f);
        }
    }
    acc.x += __shfl_xor(acc.x, 8, 32);
    acc.y += __shfl_xor(acc.y, 8, 32);
    acc.z += __shfl_xor(acc.z, 8, 32);
    acc.w += __shfl_xor(acc.w, 8, 32);
    acc.x += __shfl_xor(acc.x, 16, 32);
    acc.y += __shfl_xor(acc.y, 16, 32);
    acc.z += __shfl_xor(acc.z, 16, 32);
    acc.w += __shfl_xor(acc.w, 16, 32);

    if (sub == 0) {
        if (sl < 6) {
            float4 xn = *(const float4*)&x[(size_t)n * 27 + d0];
            float4 o;
            o.x = fmaf(onePlusEps, xn.x, acc.x);
            o.y = fmaf(onePlusEps, xn.y, acc.y);
            o.z = fmaf(onePlusEps, xn.z, acc.z);
            o.w = fmaf(onePlusEps, xn.w, acc.w);
            *(float4*)&agg[(size_t)n * 27 + d0] = o;
        } else if (sl == 6) {
            agg[(size_t)n * 27 + 24] = fmaf(onePlusEps, x[(size_t)n * 27 + 24], acc.x);
            agg[(size_t)n * 27 + 25] = fmaf(onePlusEps, x[(size_t)n * 27 + 25], acc.y);
            agg[(size_t)n * 27 + 26] = fmaf(onePlusEps, x[(size_t)n * 27 + 26], acc.z);
        }
    }
}

// ---------------------------------------------------------------- repack ALL weights (1 launch)
// 6 slots: per layer {W1: K=ind, NC=256}, {W2: K=256, NC=128}. Static geometry.
__global__ __launch_bounds__(256) void repack_all(const float* __restrict__ w0,
                                                  const float* __restrict__ w1,
                                                  const float* __restrict__ w2,
                                                  const float* __restrict__ w3,
                                                  const float* __restrict__ w4,
                                                  const float* __restrict__ w5,
                                                  ushort* __restrict__ hi,
                                                  ushort* __restrict__ lo) {
    int idx = blockIdx.x * 256 + threadIdx.x;
    if (idx >= 21504) return;
    const float* W;
    int base, K, NC;
    if (idx < 1024)       { W = w0; base = 0;     K = 27;  NC = 256; }
    else if (idx < 5120)  { W = w1; base = 1024;  K = 256; NC = 128; }
    else if (idx < 9216)  { W = w2; base = 5120;  K = 128; NC = 256; }
    else if (idx < 13312) { W = w3; base = 9216;  K = 256; NC = 128; }
    else if (idx < 17408) { W = w4; base = 13312; K = 128; NC = 256; }
    else                  { W = w5; base = 17408; K = 256; NC = 128; }
    int li = idx - base;
    int kg = (K + 31) >> 5;
    int l = li & 63;
    int g = (li >> 6) % kg;
    int t = (li >> 6) / kg;
#pragma unroll
    for (int j = 0; j < 8; ++j) {
        int k = g * 32 + ((l >> 4) << 3) + j;
        int n = (t << 4) + (l & 15);
        float v = (k < K) ? W[(size_t)k * NC + n] : 0.0f;
        ushort h = f2bf(v);
        hi[(size_t)idx * 8 + j] = h;
        lo[(size_t)idx * 8 + j] = f2bf(v - bf2f(h));
    }
}

// ---------------------------------------------------------------- MFMA GEMM (split-bf16)
// C[M, 64*NF] = pre(A[M,K]) @ W + bias, stats fused. BM=128, 512 thr = 8 waves.
// A-tile LDS rows padded to 40 shorts (80B): frag ds_read_b128 2-way (free).
// PRE_BN: computes scale/shift per-block from gemm1's sums (finalize folded in).
template <int NF, bool PRE_BN>
__global__ __launch_bounds__(512) void mfma_gemm(
    const float* __restrict__ A, int M, int K, const ushort* __restrict__ Wph,
    const ushort* __restrict__ Wpl, const float* __restrict__ bias,
    const float* __restrict__ bn_sums, const float* __restrict__ bn_sq,
    const float* __restrict__ bn_g, const float* __restrict__ bn_b, float invN,
    float* __restrict__ C, int ldc, float* __restrict__ sums, float* __restrict__ sumsq) {
    __shared__ __align__(16) ushort As_hi[128 * 40];
    __shared__ __align__(16) ushort As_lo[128 * 40];
    __shared__ float sSc[256], sSh[256];
    int tid = threadIdx.x;
    int lane = tid & 63;
    int wv = tid >> 6;
    int wm = wv >> 2, wn = wv & 3;
    int row0 = blockIdx.x * 128;
    int kg = (K + 31) >> 5;

    if (PRE_BN) {
        for (int k = tid; k < K; k += 512) {
            float mu = bn_sums[k] * invN;
            float var = bn_sq[k] * invN - mu * mu;
            float inv = rsqrtf(var + 1e-5f);
            float sc = bn_g[k] * inv;
            sSc[k] = sc;
            sSh[k] = bn_b[k] - mu * sc;
        }
        __syncthreads();
    }

    f32x4 acc[4][NF] = {};

    for (int g = 0; g < kg; ++g) {
        int k0 = g << 5;
        for (int c = tid; c < 1024; c += 512) {
            int row = c >> 3;
            int kc = (c & 7) << 2;
            int gm = row0 + row;
            float v[4] = {0.f, 0.f, 0.f, 0.f};
            if (gm < M) {
                const float* ap = &A[(size_t)gm * K + k0 + kc];
                if (k0 + kc + 4 <= K) {
                    float4 t4 = *(const float4*)ap;
                    v[0] = t4.x; v[1] = t4.y; v[2] = t4.z; v[3] = t4.w;
                } else {
#pragma unroll
                    for (int t = 0; t < 4; ++t)
                        if (k0 + kc + t < K) v[t] = ap[t];
                }
                if (PRE_BN) {
#pragma unroll
                    for (int t = 0; t < 4; ++t) {
                        int k = k0 + kc + t;
                        if (k < K) v[t] = fmaxf(fmaf(v[t], sSc[k], sSh[k]), 0.0f);
                    }
                }
            }
            ushort h[4], l2[4];
#pragma unroll
            for (int t = 0; t < 4; ++t) {
                h[t] = f2bf(v[t]);
                l2[t] = f2bf(v[t] - bf2f(h[t]));
            }
            int e = row * 40 + kc;
            *(ushort4*)&As_hi[e] = make_ushort4(h[0], h[1], h[2], h[3]);
            *(ushort4*)&As_lo[e] = make_ushort4(l2[0], l2[1], l2[2], l2[3]);
        }
        __syncthreads();

        bf16x8 ah[4], al[4];
#pragma unroll
        for (int mf = 0; mf < 4; ++mf) {
            int e = ((wm << 6) + (mf << 4) + (lane & 15)) * 40 + ((lane >> 4) << 3);
            ah[mf] = *(const bf16x8*)&As_hi[e];
            al[mf] = *(const bf16x8*)&As_lo[e];
        }
#pragma unroll
        for (int nf = 0; nf < NF; ++nf) {
            int tn = wn * NF + nf;
            size_t off = (((size_t)tn * kg + g) * 64 + lane) * 8;
            bf16x8 bh = *(const bf16x8*)(Wph + off);
            bf16x8 bl = *(const bf16x8*)(Wpl + off);
#pragma unroll
            for (int mf = 0; mf < 4; ++mf) {
                acc[mf][nf] =
                    __builtin_amdgcn_mfma_f32_16x16x32_bf16(ah[mf], bh, acc[mf][nf], 0, 0, 0);
                acc[mf][nf] =
                    __builtin_amdgcn_mfma_f32_16x16x32_bf16(ah[mf], bl, acc[mf][nf], 0, 0, 0);
                acc[mf][nf] =
                    __builtin_amdgcn_mfma_f32_16x16x32_bf16(al[mf], bh, acc[mf][nf], 0, 0, 0);
            }
        }
        __syncthreads();
    }

#pragma unroll
    for (int nf = 0; nf < NF; ++nf) {
        int col = (wn * NF + nf) * 16 + (lane & 15);
        float bv = bias[col];
        float s = 0.f, qs = 0.f;
#pragma unroll
        for (int mf = 0; mf < 4; ++mf) {
            int rbase = row0 + (wm << 6) + (mf << 4) + ((lane >> 4) << 2);
#pragma unroll
            for (int q = 0; q < 4; ++q) {
                int row = rbase + q;
                if (row < M) {
                    float v = acc[mf][nf][q] + bv;
                    C[(size_t)row * ldc + col] = v;
                    s += v;
                    qs = fmaf(v, v, qs);
                }
            }
        }
        s += __shfl_xor(s, 16);
        s += __shfl_xor(s, 32);
        qs += __shfl_xor(qs, 16);
        qs += __shfl_xor(qs, 32);
        if (lane < 16) {
            atomicAdd(&sums[col], s);
            atomicAdd(&sumsq[col], qs);
        }
    }
}

// ---------------------------------------------------------------- BN apply (finalize folded in)
template <bool RES>
__global__ __launch_bounds__(256) void bn_apply(const float* __restrict__ h,
                                                const float* __restrict__ sums,
                                                const float* __restrict__ sq,
                                                const float* __restrict__ g,
                                                const float* __restrict__ b, float invN,
                                                const float* __restrict__ xprev,
                                                float* __restrict__ out, int total4) {
    __shared__ float sSc[128], sSh[128];
    int tid = threadIdx.x;
    if (tid < 128) {
        float mu = sums[tid] * invN;
        float var = sq[tid] * invN - mu * mu;
        float inv = rsqrtf(var + 1e-5f);
        float sc = g[tid] * inv;
        sSc[tid] = sc;
        sSh[tid] = b[tid] - mu * sc;
    }
    __syncthreads();
    int i = blockIdx.x * blockDim.x + tid;
    int stride = gridDim.x * blockDim.x;
    for (; i < total4; i += stride) {
        int c0 = (i & 31) << 2;
        float4 v = ((const float4*)h)[i];
        float4 o;
        o.x = fmaxf(fmaf(v.x, sSc[c0 + 0], sSh[c0 + 0]), 0.0f);
        o.y = fmaxf(fmaf(v.y, sSc[c0 + 1], sSh[c0 + 1]), 0.0f);
        o.z = fmaxf(fmaf(v.z, sSc[c0 + 2], sSh[c0 + 2]), 0.0f);
        o.w = fmaxf(fmaf(v.w, sSc[c0 + 3], sSh[c0 + 3]), 0.0f);
        if (RES) {
            float4 xp = ((const float4*)xprev)[i];
            o.x = fmaf(0.3f, o.x, xp.x);
            o.y = fmaf(0.3f, o.y, xp.y);
            o.z = fmaf(0.3f, o.z, xp.z);
            o.w = fmaf(0.3f, o.w, xp.w);
        }
        ((float4*)out)[i] = o;
    }
}

// ---------------------------------------------------------------- launch
extern "C" void kernel_launch(void* const* d_in, const int* in_sizes, int n_in, void* d_out,
                              int out_size, void* d_ws, size_t ws_size, hipStream_t stream) {
    const float* x_in = (const float*)d_in[0];
    const int* ei = (const int*)d_in[1];
    const float* ea = (const float*)d_in[2];
    const int IN_DIM = 27;
    const int H = 128;
    int N = in_sizes[0] / IN_DIM;
    int E = in_sizes[1] / 2;
    const int* src = ei;
    const int* dst = ei + E;

    auto L = [&](int layer, int j) -> const float* {
        return (const float*)d_in[3 + 11 * layer + j];
    };
    // j: 0 eps, 1 eW, 2 eb, 3 W1, 4 b1, 5 g1, 6 be1, 7 W2, 8 b2, 9 ng, 10 nb

    float* X0 = (float*)d_ws;         // [N,128]
    float* AGG = X0 + (size_t)N * H;  // [N,128] (also h2)
    float* H1 = AGG + (size_t)N * H;  // [N,256]
    float* STATS = H1 + (size_t)N * 2 * H;  // 3 layers x 768
    int* rowptr = (int*)(STATS + 3 * 768);  // N+1
    int* cursor = rowptr + (N + 1);         // N
    int* eid = cursor + N;                  // E
    size_t wp_off = ((size_t)(eid + E - (int*)d_ws) * 4 + 15) & ~(size_t)15;
    ushort* WpH = (ushort*)((char*)d_ws + wp_off);  // 21504*8 shorts
    ushort* WpL = WpH + (size_t)21504 * 8;
    float* X1 = (float*)d_out;

    // per-slot Wp bases (x8 shorts): W1: {0,5120,13312}, W2: {1024,9216,17408}
    const size_t cum1[3] = {0, 5120, 13312};
    const size_t cum2[3] = {1024, 9216, 17408};

    float invN = 1.0f / (float)N;
    int gridM = cdiv(N, 128);
    int gatherG = cdiv(N, 8);

    // ---- CSR build + upfront repack + stats zero
    hipMemsetAsync(rowptr, 0, (size_t)(N + 1) * sizeof(int), stream);
    hipMemsetAsync(STATS, 0, 3 * 768 * sizeof(float), stream);
    histogram_dst<<<1024, 256, 0, stream>>>(dst, rowptr, E);
    repack_all<<<cdiv(21504, 256), 256, 0, stream>>>(L(0, 3), L(0, 7), L(1, 3), L(1, 7), L(2, 3),
                                                     L(2, 7), WpH, WpL);
    scan_deg<<<1, 1024, 0, stream>>>(rowptr, cursor, N);
    hipMemcpyAsync(rowptr, cursor, (size_t)(N + 1) * sizeof(int), hipMemcpyDeviceToDevice, stream);
    scatter_edges<<<1024, 256, 0, stream>>>(dst, cursor, eid, E);

    for (int i = 0; i < 3; ++i) {
        int ind = (i == 0) ? IN_DIM : H;
        const float* xin = (i == 0) ? x_in : ((i == 1) ? X0 : X1);
        float* xout = (i == 2) ? (float*)d_out : ((i == 0) ? X0 : X1);
        float* sums1 = STATS + i * 768;
        float* sq1 = sums1 + 256;
        float* sums2 = sums1 + 512;
        float* sq2 = sums1 + 640;

        if (i == 0)
            gather27<<<gatherG, 256, 0, stream>>>(rowptr, eid, src, ea, L(i, 1), L(i, 2), xin,
                                                  L(i, 0), AGG, N);
        else
            gather128<<<gatherG, 256, 0, stream>>>(rowptr, eid, src, ea, L(i, 1), L(i, 2), xin,
                                                   L(i, 0), AGG, N);

        // h1 = agg @ W1 + b1   [N,256], stats fused
        mfma_gemm<4, false><<<gridM, 512, 0, stream>>>(
            AGG, N, ind, WpH + cum1[i] * 8, WpL + cum1[i] * 8, L(i, 4), nullptr, nullptr, nullptr,
            nullptr, invN, H1, 256, sums1, sq1);

        // h2 = relu(bn1(h1)) @ W2 + b2   [N,128], finalize1 folded in, stats fused
        mfma_gemm<2, true><<<gridM, 512, 0, stream>>>(
            H1, N, 256, WpH + cum2[i] * 8, WpL + cum2[i] * 8, L(i, 8), sums1, sq1, L(i, 5),
            L(i, 6), invN, AGG, 128, sums2, sq2);

        int total4 = N * H / 4;
        if (i == 1)
            bn_apply<true><<<2048, 256, 0, stream>>>(AGG, sums2, sq2, L(i, 9), L(i, 10), invN, X0,
                                                     xout, total4);
        else
            bn_apply<false><<<2048, 256, 0, stream>>>(AGG, sums2, sq2, L(i, 9), L(i, 10), invN,
                                                      nullptr, xout, total4);
    }
}

// Round 11
// 798.635 us; speedup vs baseline: 1.0465x; 1.0465x over previous
//
#include <hip/hip_runtime.h>
#include <hip/hip_bf16.h>

// GINE backbone, 3 layers. N=50000, E=500000, IN=27, ED=12, H=128.
// Round 8 -> 9 (3rd submit; r9/r10 GPU timeouts): (1) gather128 reverted to r6
// low-VGPR body (r8 predication cost 60->80 VGPR, occupancy 34->27%,
// 84->108us); (2) GEMM stats epilogue: global fp32 atomics (780-deep
// same-address chains across XCDs) replaced by LDS-atomic block partials +
// reduce_part kernel (8 atomics/address).

typedef __attribute__((ext_vector_type(8))) short bf16x8;
typedef __attribute__((ext_vector_type(4))) float f32x4;

static inline int cdiv(int a, int b) { return (a + b - 1) / b; }

__device__ inline ushort f2bf(float f) {
    uint32_t u = __float_as_uint(f);
    return (ushort)((u + 0x7FFFu + ((u >> 16) & 1u)) >> 16);
}
__device__ inline float bf2f(ushort h) { return __uint_as_float(((uint32_t)h) << 16); }

// ---------------------------------------------------------------- CSR build
__global__ __launch_bounds__(256) void histogram_dst(const int* __restrict__ dst,
                                                     int* __restrict__ deg, int E) {
    int i = blockIdx.x * blockDim.x + threadIdx.x;
    int stride = gridDim.x * blockDim.x;
    for (; i < E; i += stride) atomicAdd(&deg[dst[i]], 1);
}

__global__ __launch_bounds__(1024) void scan_deg(const int* __restrict__ deg,
                                                 int* __restrict__ rowptr, int N) {
    __shared__ int part[1024];
    int t = threadIdx.x;
    int chunk = (N + 1023) / 1024;
    int b = t * chunk;
    int e = b + chunk;
    if (b > N) b = N;
    if (e > N) e = N;
    int s = 0;
    for (int i = b; i < e; ++i) s += deg[i];
    part[t] = s;
    __syncthreads();
    for (int off = 1; off < 1024; off <<= 1) {
        int v = (t >= off) ? part[t - off] : 0;
        __syncthreads();
        part[t] += v;
        __syncthreads();
    }
    int base = (t == 0) ? 0 : part[t - 1];
    for (int i = b; i < e; ++i) {
        rowptr[i] = base;
        base += deg[i];
    }
    if (t == 1023) rowptr[N] = base;
}

__global__ __launch_bounds__(256) void scatter_edges(const int* __restrict__ dst,
                                                     int* __restrict__ cursor,
                                                     int* __restrict__ eid, int E) {
    int i = blockIdx.x * blockDim.x + threadIdx.x;
    int stride = gridDim.x * blockDim.x;
    for (; i < E; i += stride) {
        int pos = atomicAdd(&cursor[dst[i]], 1);
        eid[pos] = i;
    }
}

// ---------------------------------------------------------------- gather IND=128 (r6 body)
// 32 lanes per node, 4 dims/lane (float4), 4 edges in flight + serial tail.
__global__ __launch_bounds__(256) void gather128(
    const int* __restrict__ rowptr, const int* __restrict__ eid, const int* __restrict__ src,
    const float* __restrict__ ea, const float* __restrict__ eW, const float* __restrict__ eb,
    const float* __restrict__ x, const float* __restrict__ epsp, float* __restrict__ agg, int N) {
    __shared__ __align__(16) float sW[12 * 128];
    __shared__ __align__(16) float sb[128];
    int tid = threadIdx.x;
    for (int i = tid; i < 12 * 128; i += 256) sW[i] = eW[i];
    if (tid < 128) sb[tid] = eb[tid];
    __syncthreads();

    float onePlusEps = 1.0f + *epsp;
    int lane = tid & 31;
    int n = blockIdx.x * 8 + (tid >> 5);
    if (n >= N) return;
    int beg = rowptr[n], end = rowptr[n + 1];
    int d0 = lane << 2;
    float4 bb = *(const float4*)&sb[d0];
    float4 acc = make_float4(0.f, 0.f, 0.f, 0.f);

    int i = beg;
    for (; i + 4 <= end; i += 4) {
        int e[4], s[4];
        float av[4];
        float4 xv[4], p[4];
#pragma unroll
        for (int j = 0; j < 4; ++j) e[j] = eid[i + j];
#pragma unroll
        for (int j = 0; j < 4; ++j) {
            s[j] = src[e[j]];
            av[j] = (lane < 12) ? ea[(size_t)e[j] * 12 + lane] : 0.0f;
        }
#pragma unroll
        for (int j = 0; j < 4; ++j) {
            xv[j] = *(const float4*)&x[(size_t)s[j] * 128 + d0];
            p[j] = bb;
        }
#pragma unroll
        for (int k = 0; k < 12; ++k) {
            float4 w = *(const float4*)&sW[k * 128 + d0];
#pragma unroll
            for (int j = 0; j < 4; ++j) {
                float a = __shfl(av[j], k, 32);
                p[j].x = fmaf(a, w.x, p[j].x);
                p[j].y = fmaf(a, w.y, p[j].y);
                p[j].z = fmaf(a, w.z, p[j].z);
                p[j].w = fmaf(a, w.w, p[j].w);
            }
        }
#pragma unroll
        for (int j = 0; j < 4; ++j) {
            acc.x += fmaxf(xv[j].x + p[j].x, 0.f);
            acc.y += fmaxf(xv[j].y + p[j].y, 0.f);
            acc.z += fmaxf(xv[j].z + p[j].z, 0.f);
            acc.w += fmaxf(xv[j].w + p[j].w, 0.f);
        }
    }
    for (; i < end; ++i) {
        int e = eid[i];
        int s = src[e];
        float av = (lane < 12) ? ea[(size_t)e * 12 + lane] : 0.0f;
        float4 p = bb;
#pragma unroll
        for (int k = 0; k < 12; ++k) {
            float ak = __shfl(av, k, 32);
            float4 w = *(const float4*)&sW[k * 128 + d0];
            p.x = fmaf(ak, w.x, p.x);
            p.y = fmaf(ak, w.y, p.y);
            p.z = fmaf(ak, w.z, p.z);
            p.w = fmaf(ak, w.w, p.w);
        }
        float4 xv = *(const float4*)&x[(size_t)s * 128 + d0];
        acc.x += fmaxf(xv.x + p.x, 0.f);
        acc.y += fmaxf(xv.y + p.y, 0.f);
        acc.z += fmaxf(xv.z + p.z, 0.f);
        acc.w += fmaxf(xv.w + p.w, 0.f);
    }
    float4 xn = *(const float4*)&x[(size_t)n * 128 + d0];
    float4 o;
    o.x = fmaf(onePlusEps, xn.x, acc.x);
    o.y = fmaf(onePlusEps, xn.y, acc.y);
    o.z = fmaf(onePlusEps, xn.z, acc.z);
    o.w = fmaf(onePlusEps, xn.w, acc.w);
    *(float4*)&agg[(size_t)n * 128 + d0] = o;
}

// ---------------------------------------------------------------- gather IND=27
__global__ __launch_bounds__(256) void gather27(
    const int* __restrict__ rowptr, const int* __restrict__ eid, const int* __restrict__ src,
    const float* __restrict__ ea, const float* __restrict__ eW, const float* __restrict__ eb,
    const float* __restrict__ x, const float* __restrict__ epsp, float* __restrict__ agg, int N) {
    __shared__ __align__(16) float sW[12 * 28 + 4];
    __shared__ __align__(16) float sb[32];
    int tid = threadIdx.x;
    for (int i = tid; i < 12 * 28 + 4; i += 256) sW[i] = 0.0f;
    if (tid < 32) sb[tid] = 0.0f;
    __syncthreads();
    for (int i = tid; i < 12 * 27; i += 256) {
        int k = i / 27, d = i - k * 27;
        sW[k * 28 + d] = eW[i];
    }
    if (tid < 27) sb[tid] = eb[tid];
    __syncthreads();

    float onePlusEps = 1.0f + *epsp;
    int lane = tid & 31;
    int n = blockIdx.x * 8 + (tid >> 5);
    if (n >= N) return;
    int beg = rowptr[n], end = rowptr[n + 1];
    int sub = lane >> 3, sl = lane & 7;
    int d0 = sl << 2;
    int d0c = (sl < 7) ? d0 : 24;
    float4 bb = *(const float4*)&sb[d0c];
    float4 acc = make_float4(0.f, 0.f, 0.f, 0.f);

    int iters = (end - beg + 3) >> 2;
    for (int it = 0; it < iters; ++it) {
        int i = beg + it * 4 + sub;
        bool v = i < end;
        int e = v ? eid[i] : 0;
        int s = v ? src[e] : 0;
        float avA = v ? ea[(size_t)e * 12 + sl] : 0.0f;
        float avB = (v && sl < 4) ? ea[(size_t)e * 12 + 8 + sl] : 0.0f;
        float4 xv = make_float4(0.f, 0.f, 0.f, 0.f);
        if (v) {
            if (sl < 6) {
                xv = *(const float4*)&x[(size_t)s * 27 + d0];
            } else if (sl == 6) {
                xv.x = x[(size_t)s * 27 + 24];
                xv.y = x[(size_t)s * 27 + 25];
                xv.z = x[(size_t)s * 27 + 26];
            }
        }
        float4 p = bb;
#pragma unroll
        for (int k = 0; k < 8; ++k) {
            float ak = __shfl(avA, k, 8);
            float4 w = *(const float4*)&sW[k * 28 + d0c];
            p.x = fmaf(ak, w.x, p.x);
            p.y = fmaf(ak, w.y, p.y);
            p.z = fmaf(ak, w.z, p.z);
            p.w = fmaf(ak, w.w, p.w);
        }
#pragma unroll
        for (int k = 8; k < 12; ++k) {
            float ak = __shfl(avB, k - 8, 8);
            float4 w = *(const float4*)&sW[k * 28 + d0c];
            p.x = fmaf(ak, w.x, p.x);
            p.y = fmaf(ak, w.y, p.y);
            p.z = fmaf(ak, w.z, p.z);
            p.w = fmaf(ak, w.w, p.w);
        }
        if (v) {
            acc.x += fmaxf(xv.x + p.x, 0.f);
            acc.y += fmaxf(xv.y + p.y, 0.f);
            acc.z += fmaxf(xv.z + p.z, 0.f);
            acc.w += fmaxf(xv.w + p.w, 0.f);
        }
    }
    acc.x += __shfl_xor(acc.x, 8, 32);
    acc.y += __shfl_xor(acc.y, 8, 32);
    acc.z += __shfl_xor(acc.z, 8, 32);
    acc.w += __shfl_xor(acc.w, 8, 32);
    acc.x += __shfl_xor(acc.x, 16, 32);
    acc.y += __shfl_xor(acc.y, 16, 32);
    acc.z += __shfl_xor(acc.z, 16, 32);
    acc.w += __shfl_xor(acc.w, 16, 32);

    if (sub == 0) {
        if (sl < 6) {
            float4 xn = *(const float4*)&x[(size_t)n * 27 + d0];
            float4 o;
            o.x = fmaf(onePlusEps, xn.x, acc.x);
            o.y = fmaf(onePlusEps, xn.y, acc.y);
            o.z = fmaf(onePlusEps, xn.z, acc.z);
            o.w = fmaf(onePlusEps, xn.w, acc.w);
            *(float4*)&agg[(size_t)n * 27 + d0] = o;
        } else if (sl == 6) {
            agg[(size_t)n * 27 + 24] = fmaf(onePlusEps, x[(size_t)n * 27 + 24], acc.x);
            agg[(size_t)n * 27 + 25] = fmaf(onePlusEps, x[(size_t)n * 27 + 25], acc.y);
            agg[(size_t)n * 27 + 26] = fmaf(onePlusEps, x[(size_t)n * 27 + 26], acc.z);
        }
    }
}

// ---------------------------------------------------------------- repack ALL weights (1 launch)
__global__ __launch_bounds__(256) void repack_all(const float* __restrict__ w0,
                                                  const float* __restrict__ w1,
                                                  const float* __restrict__ w2,
                                                  const float* __restrict__ w3,
                                                  const float* __restrict__ w4,
                                                  const float* __restrict__ w5,
                                                  ushort* __restrict__ hi,
                                                  ushort* __restrict__ lo) {
    int idx = blockIdx.x * 256 + threadIdx.x;
    if (idx >= 21504) return;
    const float* W;
    int base, K, NC;
    if (idx < 1024)       { W = w0; base = 0;     K = 27;  NC = 256; }
    else if (idx < 5120)  { W = w1; base = 1024;  K = 256; NC = 128; }
    else if (idx < 9216)  { W = w2; base = 5120;  K = 128; NC = 256; }
    else if (idx < 13312) { W = w3; base = 9216;  K = 256; NC = 128; }
    else if (idx < 17408) { W = w4; base = 13312; K = 128; NC = 256; }
    else                  { W = w5; base = 17408; K = 256; NC = 128; }
    int li = idx - base;
    int kg = (K + 31) >> 5;
    int l = li & 63;
    int g = (li >> 6) % kg;
    int t = (li >> 6) / kg;
#pragma unroll
    for (int j = 0; j < 8; ++j) {
        int k = g * 32 + ((l >> 4) << 3) + j;
        int n = (t << 4) + (l & 15);
        float v = (k < K) ? W[(size_t)k * NC + n] : 0.0f;
        ushort h = f2bf(v);
        hi[(size_t)idx * 8 + j] = h;
        lo[(size_t)idx * 8 + j] = f2bf(v - bf2f(h));
    }
}

// ---------------------------------------------------------------- MFMA GEMM (split-bf16)
// C[M, 64*NF] = pre(A[M,K]) @ W + bias. BM=128, 512 thr = 8 waves.
// Stats: LDS-atomic block reduction -> per-block partials (NO global fp32 atomics).
template <int NF, bool PRE_BN>
__global__ __launch_bounds__(512) void mfma_gemm(
    const float* __restrict__ A, int M, int K, const ushort* __restrict__ Wph,
    const ushort* __restrict__ Wpl, const float* __restrict__ bias,
    const float* __restrict__ bn_sums, const float* __restrict__ bn_sq,
    const float* __restrict__ bn_g, const float* __restrict__ bn_b, float invN,
    float* __restrict__ C, int ldc, float* __restrict__ part) {
    constexpr int NCOLS = 16 * 4 * NF;  // 256 (NF=4) or 128 (NF=2)
    __shared__ __align__(16) ushort As_hi[128 * 40];
    __shared__ __align__(16) ushort As_lo[128 * 40];
    __shared__ float sSc[256], sSh[256];
    __shared__ float sStat[2 * NCOLS];
    int tid = threadIdx.x;
    int lane = tid & 63;
    int wv = tid >> 6;
    int wm = wv >> 2, wn = wv & 3;
    int row0 = blockIdx.x * 128;
    int kg = (K + 31) >> 5;

    if (PRE_BN) {
        for (int k = tid; k < K; k += 512) {
            float mu = bn_sums[k] * invN;
            float var = bn_sq[k] * invN - mu * mu;
            float inv = rsqrtf(var + 1e-5f);
            float sc = bn_g[k] * inv;
            sSc[k] = sc;
            sSh[k] = bn_b[k] - mu * sc;
        }
    }
    for (int i = tid; i < 2 * NCOLS; i += 512) sStat[i] = 0.0f;
    __syncthreads();

    f32x4 acc[4][NF] = {};

    for (int g = 0; g < kg; ++g) {
        int k0 = g << 5;
        for (int c = tid; c < 1024; c += 512) {
            int row = c >> 3;
            int kc = (c & 7) << 2;
            int gm = row0 + row;
            float v[4] = {0.f, 0.f, 0.f, 0.f};
            if (gm < M) {
                const float* ap = &A[(size_t)gm * K + k0 + kc];
                if (k0 + kc + 4 <= K) {
                    float4 t4 = *(const float4*)ap;
                    v[0] = t4.x; v[1] = t4.y; v[2] = t4.z; v[3] = t4.w;
                } else {
#pragma unroll
                    for (int t = 0; t < 4; ++t)
                        if (k0 + kc + t < K) v[t] = ap[t];
                }
                if (PRE_BN) {
#pragma unroll
                    for (int t = 0; t < 4; ++t) {
                        int k = k0 + kc + t;
                        if (k < K) v[t] = fmaxf(fmaf(v[t], sSc[k], sSh[k]), 0.0f);
                    }
                }
            }
            ushort h[4], l2[4];
#pragma unroll
            for (int t = 0; t < 4; ++t) {
                h[t] = f2bf(v[t]);
                l2[t] = f2bf(v[t] - bf2f(h[t]));
            }
            int e = row * 40 + kc;
            *(ushort4*)&As_hi[e] = make_ushort4(h[0], h[1], h[2], h[3]);
            *(ushort4*)&As_lo[e] = make_ushort4(l2[0], l2[1], l2[2], l2[3]);
        }
        __syncthreads();

        bf16x8 ah[4], al[4];
#pragma unroll
        for (int mf = 0; mf < 4; ++mf) {
            int e = ((wm << 6) + (mf << 4) + (lane & 15)) * 40 + ((lane >> 4) << 3);
            ah[mf] = *(const bf16x8*)&As_hi[e];
            al[mf] = *(const bf16x8*)&As_lo[e];
        }
#pragma unroll
        for (int nf = 0; nf < NF; ++nf) {
            int tn = wn * NF + nf;
            size_t off = (((size_t)tn * kg + g) * 64 + lane) * 8;
            bf16x8 bh = *(const bf16x8*)(Wph + off);
            bf16x8 bl = *(const bf16x8*)(Wpl + off);
#pragma unroll
            for (int mf = 0; mf < 4; ++mf) {
                acc[mf][nf] =
                    __builtin_amdgcn_mfma_f32_16x16x32_bf16(ah[mf], bh, acc[mf][nf], 0, 0, 0);
                acc[mf][nf] =
                    __builtin_amdgcn_mfma_f32_16x16x32_bf16(ah[mf], bl, acc[mf][nf], 0, 0, 0);
                acc[mf][nf] =
                    __builtin_amdgcn_mfma_f32_16x16x32_bf16(al[mf], bh, acc[mf][nf], 0, 0, 0);
            }
        }
        __syncthreads();
    }

    // epilogue: bias, store, stats into LDS (D: col=lane&15, row=(lane>>4)*4+q)
#pragma unroll
    for (int nf = 0; nf < NF; ++nf) {
        int col = (wn * NF + nf) * 16 + (lane & 15);
        float bv = bias[col];
        float s = 0.f, qs = 0.f;
#pragma unroll
        for (int mf = 0; mf < 4; ++mf) {
            int rbase = row0 + (wm << 6) + (mf << 4) + ((lane >> 4) << 2);
#pragma unroll
            for (int q = 0; q < 4; ++q) {
                int row = rbase + q;
                if (row < M) {
                    float v = acc[mf][nf][q] + bv;
                    C[(size_t)row * ldc + col] = v;
                    s += v;
                    qs = fmaf(v, v, qs);
                }
            }
        }
        s += __shfl_xor(s, 16);
        s += __shfl_xor(s, 32);
        qs += __shfl_xor(qs, 16);
        qs += __shfl_xor(qs, 32);
        if (lane < 16) {
            atomicAdd(&sStat[col], s);
            atomicAdd(&sStat[NCOLS + col], qs);
        }
    }
    __syncthreads();
    float* pb = part + (size_t)blockIdx.x * 2 * NCOLS;
    for (int i = tid; i < 2 * NCOLS; i += 512) pb[i] = sStat[i];
}

// ---------------------------------------------------------------- partial reduce
// out[col] += sum_b part[b*width + col]; grid (cdiv(width,256), 8) -> 8 atomics/addr.
__global__ __launch_bounds__(256) void reduce_part(const float* __restrict__ part, int nblocks,
                                                   int width, float* __restrict__ out) {
    int col = blockIdx.x * 256 + threadIdx.x;
    if (col >= width) return;
    int per = (nblocks + gridDim.y - 1) / gridDim.y;
    int b0 = blockIdx.y * per;
    int b1 = b0 + per;
    if (b1 > nblocks) b1 = nblocks;
    float s = 0.0f;
    for (int b = b0; b < b1; ++b) s += part[(size_t)b * width + col];
    atomicAdd(&out[col], s);
}

// ---------------------------------------------------------------- BN apply (finalize folded in)
template <bool RES>
__global__ __launch_bounds__(256) void bn_apply(const float* __restrict__ h,
                                                const float* __restrict__ sums,
                                                const float* __restrict__ sq,
                                                const float* __restrict__ g,
                                                const float* __restrict__ b, float invN,
                                                const float* __restrict__ xprev,
                                                float* __restrict__ out, int total4) {
    __shared__ float sSc[128], sSh[128];
    int tid = threadIdx.x;
    if (tid < 128) {
        float mu = sums[tid] * invN;
        float var = sq[tid] * invN - mu * mu;
        float inv = rsqrtf(var + 1e-5f);
        float sc = g[tid] * inv;
        sSc[tid] = sc;
        sSh[tid] = b[tid] - mu * sc;
    }
    __syncthreads();
    int i = blockIdx.x * blockDim.x + tid;
    int stride = gridDim.x * blockDim.x;
    for (; i < total4; i += stride) {
        int c0 = (i & 31) << 2;
        float4 v = ((const float4*)h)[i];
        float4 o;
        o.x = fmaxf(fmaf(v.x, sSc[c0 + 0], sSh[c0 + 0]), 0.0f);
        o.y = fmaxf(fmaf(v.y, sSc[c0 + 1], sSh[c0 + 1]), 0.0f);
        o.z = fmaxf(fmaf(v.z, sSc[c0 + 2], sSh[c0 + 2]), 0.0f);
        o.w = fmaxf(fmaf(v.w, sSc[c0 + 3], sSh[c0 + 3]), 0.0f);
        if (RES) {
            float4 xp = ((const float4*)xprev)[i];
            o.x = fmaf(0.3f, o.x, xp.x);
            o.y = fmaf(0.3f, o.y, xp.y);
            o.z = fmaf(0.3f, o.z, xp.z);
            o.w = fmaf(0.3f, o.w, xp.w);
        }
        ((float4*)out)[i] = o;
    }
}

// ---------------------------------------------------------------- launch
extern "C" void kernel_launch(void* const* d_in, const int* in_sizes, int n_in, void* d_out,
                              int out_size, void* d_ws, size_t ws_size, hipStream_t stream) {
    const float* x_in = (const float*)d_in[0];
    const int* ei = (const int*)d_in[1];
    const float* ea = (const float*)d_in[2];
    const int IN_DIM = 27;
    const int H = 128;
    int N = in_sizes[0] / IN_DIM;
    int E = in_sizes[1] / 2;
    const int* src = ei;
    const int* dst = ei + E;

    auto L = [&](int layer, int j) -> const float* {
        return (const float*)d_in[3 + 11 * layer + j];
    };
    // j: 0 eps, 1 eW, 2 eb, 3 W1, 4 b1, 5 g1, 6 be1, 7 W2, 8 b2, 9 ng, 10 nb

    float* X0 = (float*)d_ws;         // [N,128]
    float* AGG = X0 + (size_t)N * H;  // [N,128] (also h2)
    float* H1 = AGG + (size_t)N * H;  // [N,256]
    float* STATS = H1 + (size_t)N * 2 * H;  // 3 layers x 768
    int* rowptr = (int*)(STATS + 3 * 768);  // N+1
    int* cursor = rowptr + (N + 1);         // N
    int* eid = cursor + N;                  // E
    size_t wp_off = ((size_t)(eid + E - (int*)d_ws) * 4 + 15) & ~(size_t)15;
    ushort* WpH = (ushort*)((char*)d_ws + wp_off);  // 21504*8 shorts
    ushort* WpL = WpH + (size_t)21504 * 8;
    float* PART = (float*)(WpL + (size_t)21504 * 8);  // gridM * 512 floats
    float* X1 = (float*)d_out;

    const size_t cum1[3] = {0, 5120, 13312};
    const size_t cum2[3] = {1024, 9216, 17408};

    float invN = 1.0f / (float)N;
    int gridM = cdiv(N, 128);
    int gatherG = cdiv(N, 8);

    // ---- CSR build + upfront repack + stats zero
    hipMemsetAsync(rowptr, 0, (size_t)(N + 1) * sizeof(int), stream);
    hipMemsetAsync(STATS, 0, 3 * 768 * sizeof(float), stream);
    histogram_dst<<<1024, 256, 0, stream>>>(dst, rowptr, E);
    repack_all<<<cdiv(21504, 256), 256, 0, stream>>>(L(0, 3), L(0, 7), L(1, 3), L(1, 7), L(2, 3),
                                                     L(2, 7), WpH, WpL);
    scan_deg<<<1, 1024, 0, stream>>>(rowptr, cursor, N);
    hipMemcpyAsync(rowptr, cursor, (size_t)(N + 1) * sizeof(int), hipMemcpyDeviceToDevice, stream);
    scatter_edges<<<1024, 256, 0, stream>>>(dst, cursor, eid, E);

    for (int i = 0; i < 3; ++i) {
        int ind = (i == 0) ? IN_DIM : H;
        const float* xin = (i == 0) ? x_in : ((i == 1) ? X0 : X1);
        float* xout = (i == 2) ? (float*)d_out : ((i == 0) ? X0 : X1);
        float* sums1 = STATS + i * 768;
        float* sq1 = sums1 + 256;
        float* sums2 = sums1 + 512;
        float* sq2 = sums1 + 640;

        if (i == 0)
            gather27<<<gatherG, 256, 0, stream>>>(rowptr, eid, src, ea, L(i, 1), L(i, 2), xin,
                                                  L(i, 0), AGG, N);
        else
            gather128<<<gatherG, 256, 0, stream>>>(rowptr, eid, src, ea, L(i, 1), L(i, 2), xin,
                                                   L(i, 0), AGG, N);

        // h1 = agg @ W1 + b1   [N,256], partial stats
        mfma_gemm<4, false><<<gridM, 512, 0, stream>>>(
            AGG, N, ind, WpH + cum1[i] * 8, WpL + cum1[i] * 8, L(i, 4), nullptr, nullptr, nullptr,
            nullptr, invN, H1, 256, PART);
        reduce_part<<<dim3(2, 8), 256, 0, stream>>>(PART, gridM, 512, sums1);

        // h2 = relu(bn1(h1)) @ W2 + b2   [N,128], finalize1 folded in, partial stats
        mfma_gemm<2, true><<<gridM, 512, 0, stream>>>(
            H1, N, 256, WpH + cum2[i] * 8, WpL + cum2[i] * 8, L(i, 8), sums1, sq1, L(i, 5),
            L(i, 6), invN, AGG, 128, PART);
        reduce_part<<<dim3(1, 8), 256, 0, stream>>>(PART, gridM, 256, sums2);

        int total4 = N * H / 4;
        if (i == 1)
            bn_apply<true><<<2048, 256, 0, stream>>>(AGG, sums2, sq2, L(i, 9), L(i, 10), invN, X0,
                                                     xout, total4);
        else
            bn_apply<false><<<2048, 256, 0, stream>>>(AGG, sums2, sq2, L(i, 9), L(i, 10), invN,
                                                      nullptr, xout, total4);
    }
}